// Round 3
// baseline (1619.339 us; speedup 1.0000x reference)
//
#include <hip/hip_runtime.h>
#include <math.h>

// DomainTransformFilter on [8,3,1024,1024] f32.
// = 6 separable 61-tap Gaussian conv passes (sigma 10/20/40, H+V, replicate
// pad); edge-weight multiplies s = w/(w+1e-8) are within 7.4e-8 of 1 and are
// dropped (bound verified rounds 1-2, absmax 3.9e-3 = fp32 ordering only).
//
// Round-3 structure: make the per-CU LDS pipe demand << VALU demand.
//  - hconv stages the tile TRANSPOSED (tile_t[x][y], stride 65; odd stride
//    => both transposing writes and column reads are bank-conflict-free).
//    Compute lanes span y (stride-1), each thread slides a window along x
//    producing 32 outputs (92 b32 reads / 32 outs = 12 B/out).
//  - vconv keeps row-major tile; threads own an x-PAIR (float2 = b64 reads,
//    bank-floor optimal) x 16 y-outputs (76 b64 / 32 outs = 12 B/out).
// LDS pipe/CU drops to ~46-55% of VALU demand (was ~90%), so the 61-FMA/out
// vector work can saturate issue.

#define HH 1024
#define WW 1024
#define BB 8
#define CC 3
#define KS 61
#define HK 30

struct GW { float w[KS]; };   // by value -> kernarg -> SGPR weights

// ---------------------------------------------------------------------------
// Horizontal conv, transposed tile. Block: 256 thr = 64 y-lanes x 4 x-groups.
// Out: 128 x X 64 y per block. Tile: 192 x-rows X 64 y, stride 65.
// LDS 49920 B -> 3 blocks/CU. Window: j in [2,93], tap t = j - i - 2.
// ---------------------------------------------------------------------------
__global__ __launch_bounds__(256) void hconv(const float* __restrict__ in,
                                             float* __restrict__ out, GW g) {
    __shared__ float tile[192 * 65];        // [x_row][y] stride 65
    const int xt  = blockIdx.x;             // 0..7
    const int yt  = blockIdx.y;             // 0..15
    const int bc  = blockIdx.z;
    const int tid = threadIdx.x;

    const float* src   = in + (size_t)bc * (HH * (size_t)WW);
    const int    y0    = yt * 64;
    const int    xbase = xt * 128 - 32;     // tile row 0 <-> global x = xbase

    // stage + transpose: float4 global reads (16 lanes x 16B = 256B segs),
    // 4 scattered b32 LDS writes each (banks (4xq+e+y)%32: all 32, 2x: free)
    {
        const int xq0 = tid & 15;
        const int yy0 = tid >> 4;
        #pragma unroll
        for (int m = 0; m < 4; ++m) {
            const int y = yy0 + 16 * m;
            const float* srow = src + (size_t)(y0 + y) * WW;
            #pragma unroll
            for (int k = 0; k < 3; ++k) {
                const int xq = xq0 + 16 * k;           // 0..47
                const int gx = xbase + 4 * xq;
                float v0, v1, v2, v3;
                if (gx >= 0 && gx + 3 < WW) {
                    const float4 v = *(const float4*)(srow + gx);
                    v0 = v.x; v1 = v.y; v2 = v.z; v3 = v.w;
                } else {                               // replicate pad
                    v0 = srow[min(max(gx + 0, 0), WW - 1)];
                    v1 = srow[min(max(gx + 1, 0), WW - 1)];
                    v2 = srow[min(max(gx + 2, 0), WW - 1)];
                    v3 = srow[min(max(gx + 3, 0), WW - 1)];
                }
                const int r = 4 * xq;
                tile[(r + 0) * 65 + y] = v0;
                tile[(r + 1) * 65 + y] = v1;
                tile[(r + 2) * 65 + y] = v2;
                tile[(r + 3) * 65 + y] = v3;
            }
        }
    }
    __syncthreads();

    const int y  = tid & 63;                // lane -> y (wave-uniform xg)
    const int xg = tid >> 6;                // 0..3, 32 out x each

    float acc[32];
    #pragma unroll
    for (int i = 0; i < 32; ++i) acc[i] = 0.f;

    const float* tbase = &tile[32 * xg * 65 + y];
    #pragma unroll
    for (int j = 2; j <= 93; ++j) {         // 92 stride-1-lane b32 reads
        const float v = tbase[j * 65];
        #pragma unroll
        for (int i = 0; i < 32; ++i) {
            const int t = j - i - 2;
            if (t >= 0 && t < KS)
                acc[i] = fmaf(g.w[t], v, acc[i]);
        }
    }

    float* dst = out + (size_t)bc * (HH * (size_t)WW)
                     + (size_t)(y0 + y) * WW + xt * 128 + 32 * xg;
    #pragma unroll
    for (int i = 0; i < 8; ++i)
        *(float4*)(dst + 4 * i) = make_float4(acc[4*i], acc[4*i+1],
                                              acc[4*i+2], acc[4*i+3]);
}

// ---------------------------------------------------------------------------
// Vertical conv. Block: 256 thr = 32 x-pairs x 8 y-groups.
// Out: 64 x X 128 y per block. Tile: 188 y-rows X 64 x = 48128 B -> 3/CU.
// Each thread: float2 across x, 16 y-outputs, 76 b64 window reads.
// ---------------------------------------------------------------------------
__global__ __launch_bounds__(256) void vconv(const float* __restrict__ in,
                                             float* __restrict__ out, GW g) {
    __shared__ float tile[188 * 64];
    const int bx0 = blockIdx.x * 64;
    const int ty0 = blockIdx.y * 128;
    const int bc  = blockIdx.z;
    const int tid = threadIdx.x;

    const float* src = in + (size_t)bc * (HH * (size_t)WW);

    {   // stage: float2 per lane (32 lanes x 8B = 256B segments), b64 writes
        const int xp = tid & 31, rowg = tid >> 5;      // 8 row-groups
        #pragma unroll
        for (int k = 0; k < 24; ++k) {
            const int r = rowg + 8 * k;
            if (r < 188) {
                const int gy = min(max(ty0 + r - HK, 0), HH - 1);
                *(float2*)&tile[r * 64 + 2 * xp] =
                    *(const float2*)(src + (size_t)gy * WW + bx0 + 2 * xp);
            }
        }
    }
    __syncthreads();

    const int xp = tid & 31;
    const int yg = tid >> 5;                // 0..7
    const int yo = yg * 16;

    float2 acc[16];
    #pragma unroll
    for (int i = 0; i < 16; ++i) { acc[i].x = 0.f; acc[i].y = 0.f; }

    const float* tbase = &tile[yo * 64 + 2 * xp];
    #pragma unroll
    for (int j = 0; j < 76; ++j) {          // b64 reads, bank-floor optimal
        const float2 v = *(const float2*)(tbase + j * 64);
        #pragma unroll
        for (int i = 0; i < 16; ++i) {
            const int t = j - i;
            if (t >= 0 && t < KS) {
                acc[i].x = fmaf(g.w[t], v.x, acc[i].x);
                acc[i].y = fmaf(g.w[t], v.y, acc[i].y);
            }
        }
    }

    float* dst = out + (size_t)bc * (HH * (size_t)WW)
                     + (size_t)(ty0 + yo) * WW + bx0 + 2 * xp;
    #pragma unroll
    for (int i = 0; i < 16; ++i)
        *(float2*)(dst + (size_t)i * WW) = acc[i];
}

// ---------------------------------------------------------------------------
static void fill_w(double sigma, GW* g) {
    double tmp[KS], s = 0.0;
    for (int k = 0; k < KS; ++k) {
        const double d = (double)(k - HK);
        tmp[k] = exp(-(d * d) / (2.0 * sigma * sigma));
        s += tmp[k];
    }
    for (int k = 0; k < KS; ++k) g->w[k] = (float)(tmp[k] / s);
}

extern "C" void kernel_launch(void* const* d_in, const int* in_sizes, int n_in,
                              void* d_out, int out_size, void* d_ws, size_t ws_size,
                              hipStream_t stream) {
    const float* input = (const float*)d_in[0];
    float* out = (float*)d_out;
    float* tmp = (float*)d_ws;              // 96 MiB scratch

    GW g10, g20, g40;
    fill_w(10.0, &g10);
    fill_w(20.0, &g20);
    fill_w(40.0, &g40);

    const dim3 hb(256), hg(WW / 128, HH / 64, BB * CC);   // 8x16x24 = 3072
    const dim3 vb(256), vg(WW / 64, HH / 128, BB * CC);   // 16x8x24 = 3072

    hconv<<<hg, hb, 0, stream>>>(input, tmp, g10);
    vconv<<<vg, vb, 0, stream>>>(tmp, out, g10);
    hconv<<<hg, hb, 0, stream>>>(out, tmp, g20);
    vconv<<<vg, vb, 0, stream>>>(tmp, out, g20);
    hconv<<<hg, hb, 0, stream>>>(out, tmp, g40);
    vconv<<<vg, vb, 0, stream>>>(tmp, out, g40);
}

// Round 4
// 508.538 us; speedup vs baseline: 3.1843x; 3.1843x over previous
//
#include <hip/hip_runtime.h>
#include <math.h>

// DomainTransformFilter on [8,3,1024,1024] f32.
//
// Reference = 3 iterations of {61-tap H Gaussian, 61-tap V Gaussian}, each
// with replicate padding, sigma 10/20/40 (all truncate to ks=61). The
// edge-weight multiplies s = w/(w+1e-8) deviate from 1 by < 7.4e-8 and are
// dropped (verified rounds 1-3).
//
// With s dropped every pass is linear: Out = Mv * X * Mh^T, so the three H
// ops and three V ops commute EXACTLY (including clamp boundaries - they are
// pure row-space / col-space operators). We compose the three 61-tap kernels
// into one 181-tap kernel (host, double precision) and run TWO passes.
// The composite equals the sequential-clamped operator for pixels >= 90 from
// an edge; the outer 96-px strips are computed exactly by small sequential
// 3-stage kernels (hedge/vedge), and the interior kernels skip them.
//
// Round-3 lesson (VALUBusy*dur = 5x FMA floor): window loops must stay
// <= ~800 compile-time FMA slots or LLVM abandons full unroll and the
// guards/weights go runtime. All loops below are chunked accordingly.

#define HH 1024
#define WW 1024
#define BB 8
#define CC 3
#define KC 181          // composite taps
#define HKC 90

struct GWC { float w[KC]; };                    // composite, by value -> SGPRs
struct GW3 { float w10[61], w20[61], w40[61]; };

// ---- shared window-compute macro: 16 accs, float2 reads along the window --
// tb: 8B-aligned pointer to &tile[lane*310 + 16*grp]; taps t = j - i, j=2jp(+1)
#define WCHUNK(JP0, JP1)                                                     \
    _Pragma("unroll")                                                        \
    for (int jp = (JP0); jp < (JP1); ++jp) {                                 \
        const float2 v = *(const float2*)(tb + 2 * jp);                      \
        _Pragma("unroll")                                                    \
        for (int i = 0; i < 16; ++i) {                                       \
            const int t0 = 2 * jp - i;                                       \
            if (t0 >= 0 && t0 < KC) acc[i] = fmaf(g.w[t0], v.x, acc[i]);     \
            const int t1 = 2 * jp + 1 - i;                                   \
            if (t1 >= 0 && t1 < KC) acc[i] = fmaf(g.w[t1], v.y, acc[i]);     \
        }                                                                    \
    }

// ---------------------------------------------------------------------------
// Interior horizontal composite conv. Block 512 = 64 y-lanes x 8 x-groups.
// Out 128x x 64y. Tile [64 y][310] (308 staged cols), stride 310: gcd 32 = 2
// -> 2 lanes/bank = free; even -> b64-aligned rows. LDS 79360 B -> 2 blk/CU.
// ---------------------------------------------------------------------------
__global__ __launch_bounds__(512) void hconv(const float* __restrict__ in,
                                             float* __restrict__ out, GWC g) {
    __shared__ float tile[64 * 310];
    const int xt = blockIdx.x, yt = blockIdx.y, bc = blockIdx.z;
    const int tid = threadIdx.x;
    const int y0 = yt * 64;
    const int xbase = xt * 128 - HKC;           // tile col 0 <-> global x (even)
    const float* src = in + (size_t)bc * (HH * (size_t)WW);

    {   // stage: float2 global -> b64 LDS, 154 pairs per row
        const int rg = tid >> 6, lane = tid & 63;
        #pragma unroll
        for (int k = 0; k < 8; ++k) {
            const int r = rg + 8 * k;
            const float* srow = src + (size_t)(y0 + r) * WW;
            #pragma unroll
            for (int m = 0; m < 3; ++m) {
                const int cp = lane + 64 * m;   // pair index
                if (cp < 154) {
                    const int gx = xbase + 2 * cp;
                    float2 v;
                    if (gx >= 0 && gx + 1 < WW) v = *(const float2*)(srow + gx);
                    else {
                        v.x = srow[min(max(gx + 0, 0), WW - 1)];
                        v.y = srow[min(max(gx + 1, 0), WW - 1)];
                    }
                    *(float2*)&tile[r * 310 + 2 * cp] = v;
                }
            }
        }
    }
    __syncthreads();

    const int y = tid & 63, xg = tid >> 6;      // xg wave-uniform
    // edge strips [0,96) and [928,1024) are owned by hedge (exact sequential)
    if ((xt == 0 && xg < 6) || (xt == 7 && xg >= 2)) return;

    float acc[16];
    #pragma unroll
    for (int i = 0; i < 16; ++i) acc[i] = 0.f;

    const float* tb = &tile[y * 310 + 16 * xg];
    WCHUNK(0, 25) WCHUNK(25, 49) WCHUNK(49, 74) WCHUNK(74, 98)

    float* dst = out + (size_t)bc * (HH * (size_t)WW)
                     + (size_t)(y0 + y) * WW + xt * 128 + 16 * xg;
    #pragma unroll
    for (int i = 0; i < 4; ++i)
        *(float4*)(dst + 4 * i) = make_float4(acc[4*i], acc[4*i+1],
                                              acc[4*i+2], acc[4*i+3]);
}

// ---------------------------------------------------------------------------
// Interior vertical composite conv: tile staged TRANSPOSED -> identical
// compute structure to hconv. Block 512 = 64 x-lanes x 8 y-groups.
// Out 64x x 128y. Tile [64 x][310 rows]. LDS 79360 B -> 2 blk/CU.
// ---------------------------------------------------------------------------
__global__ __launch_bounds__(512) void vconv(const float* __restrict__ in,
                                             float* __restrict__ out, GWC g) {
    __shared__ float tile[64 * 310];
    const int xt = blockIdx.x, yt = blockIdx.y, bc = blockIdx.z;
    const int tid = threadIdx.x;
    const int bx0 = xt * 64;
    const int ty0 = yt * 128;
    const float* src = in + (size_t)bc * (HH * (size_t)WW);

    {   // stage transposed: coalesced row reads, b32 writes (2-way = free)
        const int rg = tid >> 6, x = tid & 63;
        for (int k = 0; k < 39; ++k) {
            const int r = rg + 8 * k;           // window row
            if (r < 308) {
                const int gy = min(max(ty0 + r - HKC, 0), HH - 1);
                tile[x * 310 + r] = src[(size_t)gy * WW + bx0 + x];
            }
        }
    }
    __syncthreads();

    const int x = tid & 63, yg = tid >> 6;      // yg wave-uniform
    // edge strips y in [0,96) and [928,1024) are owned by vedge
    if ((yt == 0 && yg < 6) || (yt == 7 && yg >= 2)) return;

    float acc[16];
    #pragma unroll
    for (int i = 0; i < 16; ++i) acc[i] = 0.f;

    const float* tb = &tile[x * 310 + 16 * yg];
    WCHUNK(0, 25) WCHUNK(25, 49) WCHUNK(49, 74) WCHUNK(74, 98)

    float* dst = out + (size_t)bc * (HH * (size_t)WW)
                     + (size_t)(ty0 + 16 * yg) * WW + bx0 + x;
    #pragma unroll
    for (int i = 0; i < 16; ++i) dst[(size_t)i * WW] = acc[i];
}

// ---------------------------------------------------------------------------
// Exact sequential 3-stage H conv for the 96-px edge strips (both sides via
// mirrored indexing; all kernels are symmetric so mirror = exact).
// Block 256 = 32 y x 8 col-groups. Stages: in[0,192) -> y1[0,160) ->
// y2[0,128) (overwrites A) -> y3[0,96) -> global. LDS 45312 B -> 3 blk/CU.
// ---------------------------------------------------------------------------
__global__ __launch_bounds__(256) void hedge(const float* __restrict__ in,
                                             float* __restrict__ out, GW3 g) {
    __shared__ float A[32 * 193];
    __shared__ float B[32 * 161];
    const int side = blockIdx.x, yt = blockIdx.y, bc = blockIdx.z;
    const int tid = threadIdx.x;
    const int y0 = yt * 32;
    const float* src = in + (size_t)bc * (HH * (size_t)WW);

    {   // stage 32 rows x 192 cols (mirrored for side 1)
        const int rg = tid >> 6, lane = tid & 63;
        #pragma unroll
        for (int k = 0; k < 8; ++k) {
            const int r = rg + 4 * k;
            const float* srow = src + (size_t)(y0 + r) * WW;
            #pragma unroll
            for (int m = 0; m < 3; ++m) {
                const int c = lane + 64 * m;
                const int gx = side ? (WW - 1 - c) : c;
                A[r * 193 + c] = srow[gx];
            }
        }
    }
    __syncthreads();

    const int y = tid & 31, xg = tid >> 5;
    const float* Ay = &A[y * 193];
    float* By = &B[y * 161];

    {   // stage 1: sigma10, y1 on [0,160), 20 cols/thread
        float acc[20];
        #pragma unroll
        for (int i = 0; i < 20; ++i) acc[i] = 0.f;
        const int c0 = 20 * xg;
        #pragma unroll
        for (int j = 0; j < 40; ++j) {
            const float v = Ay[max(c0 + j - 30, 0)];
            #pragma unroll
            for (int i = 0; i < 20; ++i) {
                const int t = j - i;
                if (t >= 0 && t < 61) acc[i] = fmaf(g.w10[t], v, acc[i]);
            }
        }
        #pragma unroll
        for (int j = 40; j < 80; ++j) {
            const float v = Ay[max(c0 + j - 30, 0)];
            #pragma unroll
            for (int i = 0; i < 20; ++i) {
                const int t = j - i;
                if (t >= 0 && t < 61) acc[i] = fmaf(g.w10[t], v, acc[i]);
            }
        }
        #pragma unroll
        for (int i = 0; i < 20; ++i) By[c0 + i] = acc[i];
    }
    __syncthreads();

    {   // stage 2: sigma20, y2 on [0,128) -> A
        float acc[16];
        #pragma unroll
        for (int i = 0; i < 16; ++i) acc[i] = 0.f;
        const int c0 = 16 * xg;
        #pragma unroll
        for (int j = 0; j < 38; ++j) {
            const float v = By[max(c0 + j - 30, 0)];
            #pragma unroll
            for (int i = 0; i < 16; ++i) {
                const int t = j - i;
                if (t >= 0 && t < 61) acc[i] = fmaf(g.w20[t], v, acc[i]);
            }
        }
        #pragma unroll
        for (int j = 38; j < 76; ++j) {
            const float v = By[max(c0 + j - 30, 0)];
            #pragma unroll
            for (int i = 0; i < 16; ++i) {
                const int t = j - i;
                if (t >= 0 && t < 61) acc[i] = fmaf(g.w20[t], v, acc[i]);
            }
        }
        __syncthreads();
        float* A2 = &A[y * 193];
        #pragma unroll
        for (int i = 0; i < 16; ++i) A2[c0 + i] = acc[i];
    }
    __syncthreads();

    {   // stage 3: sigma40, y3 on [0,96) -> global (mirrored)
        float acc[12];
        #pragma unroll
        for (int i = 0; i < 12; ++i) acc[i] = 0.f;
        const int c0 = 12 * xg;
        #pragma unroll
        for (int j = 0; j < 72; ++j) {
            const float v = Ay[max(c0 + j - 30, 0)];
            #pragma unroll
            for (int i = 0; i < 12; ++i) {
                const int t = j - i;
                if (t >= 0 && t < 61) acc[i] = fmaf(g.w40[t], v, acc[i]);
            }
        }
        float* drow = out + (size_t)bc * (HH * (size_t)WW) + (size_t)(y0 + y) * WW;
        #pragma unroll
        for (int i = 0; i < 12; ++i) {
            const int gx = side ? (WW - 1 - (c0 + i)) : (c0 + i);
            drow[gx] = acc[i];
        }
    }
}

// ---------------------------------------------------------------------------
// Exact sequential 3-stage V conv for the 96-row edge strips (transposed
// layout of hedge). Block 256 = 32 x x 8 row-groups. LDS 45056 B -> 3 blk/CU.
// ---------------------------------------------------------------------------
__global__ __launch_bounds__(256) void vedge(const float* __restrict__ in,
                                             float* __restrict__ out, GW3 g) {
    __shared__ float A[192 * 32];
    __shared__ float B[160 * 32];
    const int side = blockIdx.x, xt = blockIdx.y, bc = blockIdx.z;
    const int tid = threadIdx.x;
    const int x0 = xt * 32;
    const float* src = in + (size_t)bc * (HH * (size_t)WW);

    {   // stage 192 rows x 32 cols (rows mirrored for side 1)
        const int x = tid & 31, rg = tid >> 5;
        #pragma unroll
        for (int k = 0; k < 24; ++k) {
            const int r = rg + 8 * k;
            const int gy = side ? (HH - 1 - r) : r;
            A[r * 32 + x] = src[(size_t)gy * WW + x0 + x];
        }
    }
    __syncthreads();

    const int x = tid & 31, rg = tid >> 5;

    {   // stage 1: sigma10, y1 rows [0,160)
        float acc[20];
        #pragma unroll
        for (int i = 0; i < 20; ++i) acc[i] = 0.f;
        const int r0 = 20 * rg;
        #pragma unroll
        for (int j = 0; j < 40; ++j) {
            const float v = A[max(r0 + j - 30, 0) * 32 + x];
            #pragma unroll
            for (int i = 0; i < 20; ++i) {
                const int t = j - i;
                if (t >= 0 && t < 61) acc[i] = fmaf(g.w10[t], v, acc[i]);
            }
        }
        #pragma unroll
        for (int j = 40; j < 80; ++j) {
            const float v = A[max(r0 + j - 30, 0) * 32 + x];
            #pragma unroll
            for (int i = 0; i < 20; ++i) {
                const int t = j - i;
                if (t >= 0 && t < 61) acc[i] = fmaf(g.w10[t], v, acc[i]);
            }
        }
        #pragma unroll
        for (int i = 0; i < 20; ++i) B[(r0 + i) * 32 + x] = acc[i];
    }
    __syncthreads();

    {   // stage 2: sigma20, y2 rows [0,128) -> A
        float acc[16];
        #pragma unroll
        for (int i = 0; i < 16; ++i) acc[i] = 0.f;
        const int r0 = 16 * rg;
        #pragma unroll
        for (int j = 0; j < 38; ++j) {
            const float v = B[max(r0 + j - 30, 0) * 32 + x];
            #pragma unroll
            for (int i = 0; i < 16; ++i) {
                const int t = j - i;
                if (t >= 0 && t < 61) acc[i] = fmaf(g.w20[t], v, acc[i]);
            }
        }
        #pragma unroll
        for (int j = 38; j < 76; ++j) {
            const float v = B[max(r0 + j - 30, 0) * 32 + x];
            #pragma unroll
            for (int i = 0; i < 16; ++i) {
                const int t = j - i;
                if (t >= 0 && t < 61) acc[i] = fmaf(g.w20[t], v, acc[i]);
            }
        }
        __syncthreads();
        #pragma unroll
        for (int i = 0; i < 16; ++i) A[(r0 + i) * 32 + x] = acc[i];
    }
    __syncthreads();

    {   // stage 3: sigma40, y3 rows [0,96) -> global (mirrored)
        float acc[12];
        #pragma unroll
        for (int i = 0; i < 12; ++i) acc[i] = 0.f;
        const int r0 = 12 * rg;
        #pragma unroll
        for (int j = 0; j < 72; ++j) {
            const float v = A[max(r0 + j - 30, 0) * 32 + x];
            #pragma unroll
            for (int i = 0; i < 12; ++i) {
                const int t = j - i;
                if (t >= 0 && t < 61) acc[i] = fmaf(g.w40[t], v, acc[i]);
            }
        }
        float* dimg = out + (size_t)bc * (HH * (size_t)WW);
        #pragma unroll
        for (int i = 0; i < 12; ++i) {
            const int gy = side ? (HH - 1 - (r0 + i)) : (r0 + i);
            dimg[(size_t)gy * WW + x0 + x] = acc[i];
        }
    }
}

// ---------------------------------------------------------------------------
static void make_weights(GWC* gc, GW3* g3) {
    double w[3][61];
    const double sig[3] = {10.0, 20.0, 40.0};
    for (int s = 0; s < 3; ++s) {
        double sum = 0.0;
        for (int k = 0; k < 61; ++k) {
            const double d = (double)(k - 30);
            w[s][k] = exp(-d * d / (2.0 * sig[s] * sig[s]));
            sum += w[s][k];
        }
        for (int k = 0; k < 61; ++k) w[s][k] /= sum;
    }
    double c1[121] = {0}, c2[181] = {0};
    for (int i = 0; i < 61; ++i)
        for (int j = 0; j < 61; ++j) c1[i + j] += w[0][i] * w[1][j];
    for (int i = 0; i < 121; ++i)
        for (int j = 0; j < 61; ++j) c2[i + j] += c1[i] * w[2][j];
    for (int k = 0; k < KC; ++k) gc->w[k] = (float)c2[k];
    for (int k = 0; k < 61; ++k) {
        g3->w10[k] = (float)w[0][k];
        g3->w20[k] = (float)w[1][k];
        g3->w40[k] = (float)w[2][k];
    }
}

extern "C" void kernel_launch(void* const* d_in, const int* in_sizes, int n_in,
                              void* d_out, int out_size, void* d_ws, size_t ws_size,
                              hipStream_t stream) {
    const float* input = (const float*)d_in[0];
    float* out = (float*)d_out;
    float* tmp = (float*)d_ws;                  // 96 MiB scratch

    GWC gc; GW3 g3;
    make_weights(&gc, &g3);

    // tmp = exact H result: interior composite + exact edge strips
    hconv<<<dim3(8, 16, BB * CC), 512, 0, stream>>>(input, tmp, gc);
    hedge<<<dim3(2, 32, BB * CC), 256, 0, stream>>>(input, tmp, g3);
    // out = exact V result on tmp
    vconv<<<dim3(16, 8, BB * CC), 512, 0, stream>>>(tmp, out, gc);
    vedge<<<dim3(2, 32, BB * CC), 256, 0, stream>>>(tmp, out, g3);
}